// Round 6
// baseline (7135.104 us; speedup 1.0000x reference)
//
#include <hip/hip_runtime.h>
#include <hip/hip_cooperative_groups.h>
#include <math.h>

namespace cg = cooperative_groups;

#define H 1024
#define BATCH 512
#define KSTEPS 96
#define KH ((long)KSTEPS * H)

typedef __attribute__((ext_vector_type(8))) short short8;
typedef __attribute__((ext_vector_type(4))) float f32x4;

__device__ __forceinline__ unsigned short f2bf(float x) {
    union { float f; unsigned int u; } v; v.f = x;
    unsigned int r = v.u + 0x7fffu + ((v.u >> 16) & 1u);
    return (unsigned short)(r >> 16);
}
__device__ __forceinline__ float bf2f(unsigned short h) {
    union { unsigned int u; float f; } v; v.u = ((unsigned int)h) << 16;
    return v.f;
}

// async global->LDS 16B/lane; dst wave-uniform base (HW adds lane*16)
__device__ __forceinline__ void glds16(const void* g, void* l) {
    __builtin_amdgcn_global_load_lds(
        (const __attribute__((address_space(1))) void*)g,
        (__attribute__((address_space(3))) void*)l, 16, 0, 0);
}

// ---------------------------------------------------------------------------
// Workspace layouts identical to rounds 4/5:
//   blob0/blob1: [32 t][64 by][2 s][4 jf][4 kg][16 col][8 el] bf16 frag-ordered
//   bcJ: [4096] f32 J-interleaved fused biases
//   hTa/hTb: [32 t][4 bx][2 s][8 mf][4 kg][16 row][8 el] bf16 hi/lo
// ---------------------------------------------------------------------------

__global__ void prep_w(const float* __restrict__ wih,
                       const float* __restrict__ whh,
                       unsigned short* __restrict__ blob0,
                       unsigned short* __restrict__ blob1)
{
    const unsigned int f = blockIdx.x * 256 + threadIdx.x;  // 0..2^22-1
    const int el = f & 7;
    const int col = (f >> 3) & 15;
    const int kg = (f >> 7) & 3;
    const int jf = (f >> 9) & 3;
    const int by = (f >> 11) & 63;
    const int t  = (f >> 17) & 31;
    const int b  = blockIdx.y;      // blob select

    const int J = by * 64 + jf * 16 + col;
    const int g = J & 3;
    const long j = J >> 2;
    const long k = t * 32 + kg * 8 + el;

    float v = 0.f;
    if (b == 1) {
        if (g == 0)      v = wih[j*1024 + k]           + whh[j*1024 + k];
        else if (g == 1) v = wih[(1024+j)*1024 + k]    + whh[(1024+j)*1024 + k];
        else if (g == 2) v = wih[(2048+j)*1024 + k];
        else             v = whh[(2048+j)*1024 + k];
    } else {
        if (g == 0)      v = whh[j*1024 + k];
        else if (g == 1) v = whh[(1024+j)*1024 + k];
        else if (g == 2) v = 0.f;
        else             v = whh[(2048+j)*1024 + k];
    }
    const unsigned short hi = f2bf(v);
    const unsigned short lo = f2bf(v - bf2f(hi));

    unsigned short* blob = (b == 0) ? blob0 : blob1;
    const long base = ((long)(t*64 + by)*2) * 2048 + jf*512 + kg*128 + col*8 + el;
    blob[base]        = hi;
    blob[base + 2048] = lo;
}

__global__ void prep_bcJ(const float* __restrict__ bih,
                         const float* __restrict__ bhh,
                         float* __restrict__ bcJ)
{
    const int J = blockIdx.x * 256 + threadIdx.x;   // 0..4095
    const int g = J & 3;
    const int j = J >> 2;
    float v;
    if (g == 0)      v = bih[j]        + bhh[j];
    else if (g == 1) v = bih[1024 + j] + bhh[1024 + j];
    else if (g == 2) v = bih[2048 + j];
    else             v = bhh[2048 + j];
    bcJ[J] = v;
}

// c [512][1024] fp32 -> hT fragment layout (hi/lo bf16)
__global__ void prep_h0(const float* __restrict__ c,
                        unsigned short* __restrict__ hT)
{
    const int f = blockIdx.x * 256 + threadIdx.x;   // 0..65535
    const int ko = f & 127;
    const int m  = f >> 7;
    const long k0 = (long)ko * 8;
    const int t  = ko >> 2;
    const int kg = ko & 3;
    const int bx = m >> 7;
    const int mf = (m >> 4) & 7;
    const int row = m & 15;

    unsigned short hi[8], lo[8];
    #pragma unroll
    for (int e = 0; e < 8; ++e) {
        const float v = c[(long)m*1024 + k0 + e];
        hi[e] = f2bf(v);
        lo[e] = f2bf(v - bf2f(hi[e]));
    }
    const long base = ((long)(t*4 + bx)*2) * 4096 + mf*512 + kg*128 + row*8;
    #pragma unroll
    for (int e = 0; e < 8; ++e) { hT[base + e] = hi[e]; hT[base + 4096 + e] = lo[e]; }
}

// ---------------------------------------------------------------------------
// Persistent cooperative kernel: ALL 96 GRU steps in one launch.
// Grid 256 (1 block/CU), 256 threads (4 waves). Block tile 128m x 64J.
// Per step: 32 K-chunks (W double-buffered LDS via glds16, A-frags in VGPRs
// prefetched 1 chunk ahead), fused gate epilogue -> out + next hT, then
// __threadfence + grid.sync for cross-block hT/out visibility.
// ---------------------------------------------------------------------------
__global__ __launch_bounds__(256) void gru_all(
    const unsigned short* __restrict__ blob0,
    const unsigned short* __restrict__ blob1,
    unsigned short* __restrict__ hTa,
    unsigned short* __restrict__ hTb,
    const float* __restrict__ c,
    const float* __restrict__ bcJ,
    float* __restrict__ out)
{
    cg::grid_group grid = cg::this_grid();

    __shared__ __attribute__((aligned(16))) char smem[16384]; // 2x8KB W dbuf; epilogue D reuse

    const int tid  = threadIdx.x;
    const int lane = tid & 63;
    const int wv   = tid >> 6;

    const int id   = blockIdx.x;
    const int xcd  = id & 7;
    const int slot = id >> 3;
    const int by   = xcd * 8 + (slot & 7);   // 0..63  (J tile)
    const int bx   = slot >> 3;              // 0..3   (m tile)
    const long m0  = (long)bx * 128;

    const int clo = lane & 15;
    const int chi = lane >> 4;

    float bias[4];
    #pragma unroll
    for (int jf = 0; jf < 4; ++jf) bias[jf] = bcJ[by * 64 + jf * 16 + clo];

    #pragma unroll 1
    for (int k = 0; k < KSTEPS; ++k) {
        const unsigned short* wblob = (k == 0) ? blob0 : blob1;
        const unsigned short* hTr   = (k & 1) ? hTb : hTa;
        unsigned short*       hTw   = (k & 1) ? hTa : hTb;
        const float* hprev = (k == 0) ? c : (out + (long)(k - 1) * H);
        const long hstride = (k == 0) ? (long)H : KH;
        float* outk = out + (long)k * H;

        const char* hbase = (const char*)hTr + (long)bx * 16384;   // + t*65536
        const char* wsrc  = (const char*)wblob + (long)by * 8192;  // + t*524288

        f32x4 acc[2][4];
        #pragma unroll
        for (int jf = 0; jf < 4; ++jf) {
            const float b = bias[jf];
            acc[0][jf] = (f32x4){b, b, b, b};
            acc[1][jf] = (f32x4){b, b, b, b};
        }

        auto stageW = [&](int t, char* base) {
            const char* ws = wsrc + (long)t * 524288;
            #pragma unroll
            for (int q = 0; q < 2; ++q) {
                const int seg = q * 4 + wv;
                glds16(ws + seg * 1024 + lane * 16, base + seg * 1024);
            }
        };
        auto loadA = [&](int t, short8& h0, short8& h1, short8& l0, short8& l1) {
            const char* hs = hbase + (long)t * 65536;
            h0 = *(const short8*)(hs + (2*wv + 0) * 1024 + lane * 16);
            h1 = *(const short8*)(hs + (2*wv + 1) * 1024 + lane * 16);
            l0 = *(const short8*)(hs + (8 + 2*wv + 0) * 1024 + lane * 16);
            l1 = *(const short8*)(hs + (8 + 2*wv + 1) * 1024 + lane * 16);
        };
        auto compute = [&](const char* wb, short8 ah0, short8 ah1,
                           short8 al0, short8 al1) {
            #pragma unroll
            for (int jf = 0; jf < 4; ++jf) {
                const short8 bh = *(const short8*)(wb + jf * 1024 + lane * 16);
                const short8 bl = *(const short8*)(wb + 4096 + jf * 1024 + lane * 16);
                acc[0][jf] = __builtin_amdgcn_mfma_f32_16x16x32_bf16(ah0, bh, acc[0][jf], 0, 0, 0);
                acc[0][jf] = __builtin_amdgcn_mfma_f32_16x16x32_bf16(al0, bh, acc[0][jf], 0, 0, 0);
                acc[0][jf] = __builtin_amdgcn_mfma_f32_16x16x32_bf16(ah0, bl, acc[0][jf], 0, 0, 0);
                acc[1][jf] = __builtin_amdgcn_mfma_f32_16x16x32_bf16(ah1, bh, acc[1][jf], 0, 0, 0);
                acc[1][jf] = __builtin_amdgcn_mfma_f32_16x16x32_bf16(al1, bh, acc[1][jf], 0, 0, 0);
                acc[1][jf] = __builtin_amdgcn_mfma_f32_16x16x32_bf16(ah1, bl, acc[1][jf], 0, 0, 0);
            }
        };

        short8 A0h0, A0h1, A0l0, A0l1;
        short8 A1h0, A1h1, A1l0, A1l1;

        stageW(0, smem);
        loadA(0, A0h0, A0h1, A0l0, A0l1);
        __syncthreads();

        #pragma unroll 1
        for (int tt = 0; tt < 16; ++tt) {
            {   // even chunk t = 2tt (buf0, set0)
                const int t = 2 * tt;
                stageW(t + 1, smem + 8192);
                loadA(t + 1, A1h0, A1h1, A1l0, A1l1);
                compute(smem, A0h0, A0h1, A0l0, A0l1);
                __syncthreads();
            }
            {   // odd chunk t = 2tt+1 (buf1, set1)
                if (tt < 15) {
                    const int t = 2 * tt + 1;
                    stageW(t + 1, smem);
                    loadA(t + 1, A0h0, A0h1, A0l0, A0l1);
                }
                compute(smem + 8192, A1h0, A1h1, A1l0, A1l1);
                __syncthreads();
            }
        }

        // ---- fused epilogue (bias already in acc) ----
        float* D = (float*)(smem + wv * 4096);   // [16 row][64 J] per wave

        #pragma unroll
        for (int mf = 0; mf < 2; ++mf) {
            #pragma unroll
            for (int jf = 0; jf < 4; ++jf)
                #pragma unroll
                for (int r = 0; r < 4; ++r)
                    D[(chi * 4 + r) * 64 + jf * 16 + clo] = acc[mf][jf][r];
            __syncthreads();

            #pragma unroll
            for (int q = 0; q < 4; ++q) {
                const int row16 = q * 4 + chi;
                const int jj = clo;
                const float4 gv = *(const float4*)(D + row16 * 64 + jj * 4);
                const long m = m0 + wv * 32 + mf * 16 + row16;
                const long j = (long)by * 16 + jj;

                const float hp = hprev[m * hstride + j];
                const float rr = 1.f / (1.f + expf(-gv.x));
                const float zz = 1.f / (1.f + expf(-gv.y));
                const float nn = tanhf(fmaf(rr, gv.w, gv.z));
                const float o  = nn + zz * (hp - nn);

                outk[m * KH + j] = o;

                const unsigned short hi = f2bf(o);
                const unsigned short lo = f2bf(o - bf2f(hi));
                const int t2  = by >> 1;
                const int kg2 = (int)((j & 31) >> 3);
                const long hb = ((long)(t2*4 + bx)*2) * 4096
                              + (wv*2 + mf) * 512 + kg2 * 128 + (m & 15) * 8 + (jj & 7);
                hTw[hb]        = hi;
                hTw[hb + 4096] = lo;
            }
            __syncthreads();
        }

        if (k != KSTEPS - 1) {
            __threadfence();     // device-scope: hT/out visible across XCDs
            grid.sync();
        }
    }
}

// ---------------------------------------------------------------------------
extern "C" void kernel_launch(void* const* d_in, const int* in_sizes, int n_in,
                              void* d_out, int out_size, void* d_ws, size_t ws_size,
                              hipStream_t stream)
{
    const float* c   = (const float*)d_in[0];
    // d_in[1] = K (fixed 96)
    const float* wih = (const float*)d_in[2];
    const float* whh = (const float*)d_in[3];
    const float* bih = (const float*)d_in[4];
    const float* bhh = (const float*)d_in[5];
    float* out = (float*)d_out;

    unsigned short* blob0 = (unsigned short*)d_ws;            // 8.39M ushort
    unsigned short* blob1 = blob0 + 8388608L;
    float*          bcJ   = (float*)(blob1 + 8388608L);       // 4096 f32
    unsigned short* hTa   = (unsigned short*)(bcJ + 4096);    // 1M ushort
    unsigned short* hTb   = hTa + 1048576L;

    prep_w  <<<dim3(16384, 2), 256, 0, stream>>>(wih, whh, blob0, blob1);
    prep_bcJ<<<dim3(16),       256, 0, stream>>>(bih, bhh, bcJ);
    prep_h0 <<<dim3(256),      256, 0, stream>>>(c, hTa);

    void* args[] = { (void*)&blob0, (void*)&blob1, (void*)&hTa, (void*)&hTb,
                     (void*)&c, (void*)&bcJ, (void*)&out };
    hipLaunchCooperativeKernel((const void*)gru_all, dim3(256), dim3(256),
                               args, 0, stream);
}

// Round 7
// 2096.518 us; speedup vs baseline: 3.4033x; 3.4033x over previous
//
#include <hip/hip_runtime.h>
#include <math.h>

#define H 1024
#define BATCH 512
#define KSTEPS 96
#define KH ((long)KSTEPS * H)

typedef __attribute__((ext_vector_type(8))) short short8;
typedef __attribute__((ext_vector_type(4))) float f32x4;

__device__ __forceinline__ unsigned short f2bf(float x) {
    union { float f; unsigned int u; } v; v.f = x;
    unsigned int r = v.u + 0x7fffu + ((v.u >> 16) & 1u);
    return (unsigned short)(r >> 16);
}
__device__ __forceinline__ float bf2f(unsigned short h) {
    union { unsigned int u; float f; } v; v.u = ((unsigned int)h) << 16;
    return v.f;
}

// async global->LDS 16B/lane; dst wave-uniform base (HW adds lane*16)
__device__ __forceinline__ void glds16(const void* g, void* l) {
    __builtin_amdgcn_global_load_lds(
        (const __attribute__((address_space(1))) void*)g,
        (__attribute__((address_space(3))) void*)l, 16, 0, 0);
}
#define MEMFENCE asm volatile("" ::: "memory")

// ---------------------------------------------------------------------------
// Workspace layouts identical to rounds 4/5:
//   blob0/blob1: [32 t][64 by][2 s][4 jf][4 kg][16 col][8 el] bf16 frag-ordered
//   bcJ: [4096] f32 J-interleaved fused biases
//   hTa/hTb: [32 t][4 bx][2 s][8 mf][4 kg][16 row][8 el] bf16 hi/lo
// ---------------------------------------------------------------------------

__global__ void prep_w(const float* __restrict__ wih,
                       const float* __restrict__ whh,
                       unsigned short* __restrict__ blob0,
                       unsigned short* __restrict__ blob1)
{
    const unsigned int f = blockIdx.x * 256 + threadIdx.x;  // 0..2^22-1
    const int el = f & 7;
    const int col = (f >> 3) & 15;
    const int kg = (f >> 7) & 3;
    const int jf = (f >> 9) & 3;
    const int by = (f >> 11) & 63;
    const int t  = (f >> 17) & 31;
    const int b  = blockIdx.y;      // blob select

    const int J = by * 64 + jf * 16 + col;
    const int g = J & 3;
    const long j = J >> 2;
    const long k = t * 32 + kg * 8 + el;

    float v = 0.f;
    if (b == 1) {
        if (g == 0)      v = wih[j*1024 + k]           + whh[j*1024 + k];
        else if (g == 1) v = wih[(1024+j)*1024 + k]    + whh[(1024+j)*1024 + k];
        else if (g == 2) v = wih[(2048+j)*1024 + k];
        else             v = whh[(2048+j)*1024 + k];
    } else {
        if (g == 0)      v = whh[j*1024 + k];
        else if (g == 1) v = whh[(1024+j)*1024 + k];
        else if (g == 2) v = 0.f;
        else             v = whh[(2048+j)*1024 + k];
    }
    const unsigned short hi = f2bf(v);
    const unsigned short lo = f2bf(v - bf2f(hi));

    unsigned short* blob = (b == 0) ? blob0 : blob1;
    const long base = ((long)(t*64 + by)*2) * 2048 + jf*512 + kg*128 + col*8 + el;
    blob[base]        = hi;
    blob[base + 2048] = lo;
}

__global__ void prep_bcJ(const float* __restrict__ bih,
                         const float* __restrict__ bhh,
                         float* __restrict__ bcJ)
{
    const int J = blockIdx.x * 256 + threadIdx.x;   // 0..4095
    const int g = J & 3;
    const int j = J >> 2;
    float v;
    if (g == 0)      v = bih[j]        + bhh[j];
    else if (g == 1) v = bih[1024 + j] + bhh[1024 + j];
    else if (g == 2) v = bih[2048 + j];
    else             v = bhh[2048 + j];
    bcJ[J] = v;
}

// c [512][1024] fp32 -> hT fragment layout (hi/lo bf16)
__global__ void prep_h0(const float* __restrict__ c,
                        unsigned short* __restrict__ hT)
{
    const int f = blockIdx.x * 256 + threadIdx.x;   // 0..65535
    const int ko = f & 127;
    const int m  = f >> 7;
    const long k0 = (long)ko * 8;
    const int t  = ko >> 2;
    const int kg = ko & 3;
    const int bx = m >> 7;
    const int mf = (m >> 4) & 7;
    const int row = m & 15;

    unsigned short hi[8], lo[8];
    #pragma unroll
    for (int e = 0; e < 8; ++e) {
        const float v = c[(long)m*1024 + k0 + e];
        hi[e] = f2bf(v);
        lo[e] = f2bf(v - bf2f(hi[e]));
    }
    const long base = ((long)(t*4 + bx)*2) * 4096 + mf*512 + kg*128 + row*8;
    #pragma unroll
    for (int e = 0; e < 8; ++e) { hT[base + e] = hi[e]; hT[base + 4096 + e] = lo[e]; }
}

// ---------------------------------------------------------------------------
// Fused GRU step, 3-deep counted-vmcnt pipeline, fully unrolled K-loop.
// Grid 256 (1/CU), 256 threads (4 waves). Block tile 128m x 64J.
// Per chunk t: wait vmcnt(12) [group t landed; t+1,t+2 in flight] -> raw
// s_barrier -> issue group t+3 (4 A-loads to VGPR + 2 glds16 W into 4-deep
// rotating LDS buffers) -> 24 MFMA. Groups stay in flight ~3 chunk-times
// (~1500 cyc), covering L3/HBM latency. One full drain per step (epilogue).
// ---------------------------------------------------------------------------
__global__ __launch_bounds__(256) void gru_step(
    const unsigned short* __restrict__ wblob,
    const unsigned short* __restrict__ hTr,
    unsigned short* __restrict__ hTw,
    const float* __restrict__ hprev, long hstride,
    const float* __restrict__ bcJ,
    float* __restrict__ outk)
{
    __shared__ __attribute__((aligned(16))) char smem[32768]; // 4x8KB W bufs; epi D reuse

    const int tid  = threadIdx.x;
    const int lane = tid & 63;
    const int wv   = tid >> 6;

    const int id   = blockIdx.x;
    const int xcd  = id & 7;
    const int slot = id >> 3;
    const int by   = xcd * 8 + (slot & 7);   // 0..63  (J tile)
    const int bx   = slot >> 3;              // 0..3   (m tile)
    const long m0  = (long)bx * 128;

    const char* hbase = (const char*)hTr + (long)bx * 16384;   // + t*65536
    const char* wsrc  = (const char*)wblob + (long)by * 8192;  // + t*524288

    const int clo = lane & 15;
    const int chi = lane >> 4;

    // bias folded into accumulator init: C-frag col (lane&15) selects J
    f32x4 acc[2][4];
    #pragma unroll
    for (int jf = 0; jf < 4; ++jf) {
        const float b = bcJ[by * 64 + jf * 16 + clo];
        acc[0][jf] = (f32x4){b, b, b, b};
        acc[1][jf] = (f32x4){b, b, b, b};
    }

    short8 A[4][4];   // [set = t&3][h0, h1, l0, l1]

    // issue group t: 4 A-loads (VGPR) then 2 W glds16 (LDS buf t&3)
    auto issueG = [&](int t) {
        if (t < 32) {
            const char* hs = hbase + (long)t * 65536;
            A[t & 3][0] = *(const short8*)(hs + (2*wv + 0) * 1024 + lane * 16);
            A[t & 3][1] = *(const short8*)(hs + (2*wv + 1) * 1024 + lane * 16);
            A[t & 3][2] = *(const short8*)(hs + (8 + 2*wv + 0) * 1024 + lane * 16);
            A[t & 3][3] = *(const short8*)(hs + (8 + 2*wv + 1) * 1024 + lane * 16);
            MEMFENCE;
            const char* ws = wsrc + (long)t * 524288;
            char* base = smem + (t & 3) * 8192;
            glds16(ws + (0*4 + wv) * 1024 + lane * 16, base + (0*4 + wv) * 1024);
            glds16(ws + (1*4 + wv) * 1024 + lane * 16, base + (1*4 + wv) * 1024);
            MEMFENCE;
        }
    };

    // ---- prologue: fill 3 groups ----
    issueG(0);
    issueG(1);
    issueG(2);

    // ---- fully unrolled main loop ----
    #pragma unroll
    for (int t = 0; t < 32; ++t) {
        // group t landed; keep groups t+1..t+3 in flight (6 ops each)
        if (t <= 29)      asm volatile("s_waitcnt vmcnt(12)" ::: "memory");
        else if (t == 30) asm volatile("s_waitcnt vmcnt(6)"  ::: "memory");
        else              asm volatile("s_waitcnt vmcnt(0)"  ::: "memory");
        __builtin_amdgcn_s_barrier();   // all waves: W(t) complete, W(t-1) reads done

        issueG(t + 3);                  // overwrites buf[(t-1)&3] — safe post-barrier

        const char* wb = smem + (t & 3) * 8192;
        #pragma unroll
        for (int jf = 0; jf < 4; ++jf) {
            const short8 bh = *(const short8*)(wb + jf * 1024 + lane * 16);
            const short8 bl = *(const short8*)(wb + 4096 + jf * 1024 + lane * 16);
            acc[0][jf] = __builtin_amdgcn_mfma_f32_16x16x32_bf16(A[t&3][0], bh, acc[0][jf], 0, 0, 0);
            acc[0][jf] = __builtin_amdgcn_mfma_f32_16x16x32_bf16(A[t&3][2], bh, acc[0][jf], 0, 0, 0);
            acc[0][jf] = __builtin_amdgcn_mfma_f32_16x16x32_bf16(A[t&3][0], bl, acc[0][jf], 0, 0, 0);
            acc[1][jf] = __builtin_amdgcn_mfma_f32_16x16x32_bf16(A[t&3][1], bh, acc[1][jf], 0, 0, 0);
            acc[1][jf] = __builtin_amdgcn_mfma_f32_16x16x32_bf16(A[t&3][3], bh, acc[1][jf], 0, 0, 0);
            acc[1][jf] = __builtin_amdgcn_mfma_f32_16x16x32_bf16(A[t&3][1], bl, acc[1][jf], 0, 0, 0);
        }
    }

    __syncthreads();   // full drain once; smem becomes epilogue scratch

    // ---- fused epilogue (bias already in acc) ----
    float* D = (float*)(smem + wv * 4096);   // [16 row][64 J] per wave

    #pragma unroll
    for (int mf = 0; mf < 2; ++mf) {
        #pragma unroll
        for (int jf = 0; jf < 4; ++jf)
            #pragma unroll
            for (int r = 0; r < 4; ++r)
                D[(chi * 4 + r) * 64 + jf * 16 + clo] = acc[mf][jf][r];
        __syncthreads();

        #pragma unroll
        for (int q = 0; q < 4; ++q) {
            const int row16 = q * 4 + chi;
            const int jj = clo;
            const float4 gv = *(const float4*)(D + row16 * 64 + jj * 4);
            const long m = m0 + wv * 32 + mf * 16 + row16;
            const long j = (long)by * 16 + jj;

            const float hp = hprev[m * hstride + j];
            const float rr = 1.f / (1.f + expf(-gv.x));
            const float zz = 1.f / (1.f + expf(-gv.y));
            const float nn = tanhf(fmaf(rr, gv.w, gv.z));
            const float o  = nn + zz * (hp - nn);

            outk[m * KH + j] = o;

            const unsigned short hi = f2bf(o);
            const unsigned short lo = f2bf(o - bf2f(hi));
            const int t2  = by >> 1;
            const int kg2 = (int)((j & 31) >> 3);
            const long hb = ((long)(t2*4 + bx)*2) * 4096
                          + (wv*2 + mf) * 512 + kg2 * 128 + (m & 15) * 8 + (jj & 7);
            hTw[hb]        = hi;
            hTw[hb + 4096] = lo;
        }
        __syncthreads();
    }
}

// ---------------------------------------------------------------------------
extern "C" void kernel_launch(void* const* d_in, const int* in_sizes, int n_in,
                              void* d_out, int out_size, void* d_ws, size_t ws_size,
                              hipStream_t stream)
{
    const float* c   = (const float*)d_in[0];
    // d_in[1] = K (fixed 96)
    const float* wih = (const float*)d_in[2];
    const float* whh = (const float*)d_in[3];
    const float* bih = (const float*)d_in[4];
    const float* bhh = (const float*)d_in[5];
    float* out = (float*)d_out;

    unsigned short* blob0 = (unsigned short*)d_ws;            // 8.39M ushort
    unsigned short* blob1 = blob0 + 8388608L;
    float*          bcJ   = (float*)(blob1 + 8388608L);       // 4096 f32
    unsigned short* hTa   = (unsigned short*)(bcJ + 4096);    // 1M ushort
    unsigned short* hTb   = hTa + 1048576L;

    prep_w  <<<dim3(16384, 2), 256, 0, stream>>>(wih, whh, blob0, blob1);
    prep_bcJ<<<dim3(16),       256, 0, stream>>>(bih, bhh, bcJ);
    prep_h0 <<<dim3(256),      256, 0, stream>>>(c, hTa);

    for (int k = 0; k < KSTEPS; ++k) {
        const unsigned short* wb  = (k == 0) ? blob0 : blob1;
        const unsigned short* hTr = (k & 1) ? hTb : hTa;
        unsigned short*       hTw = (k & 1) ? hTa : hTb;
        const float* hprev = (k == 0) ? c : (out + (long)(k - 1) * H);
        const long hstride = (k == 0) ? (long)H : KH;
        gru_step<<<dim3(256), 256, 0, stream>>>(wb, hTr, hTw, hprev, hstride,
                                                bcJ, out + (long)k * H);
    }
}

// Round 8
// 1650.578 us; speedup vs baseline: 4.3228x; 1.2702x over previous
//
#include <hip/hip_runtime.h>
#include <math.h>

#define H 1024
#define BATCH 512
#define KSTEPS 96
#define KH ((long)KSTEPS * H)

typedef __attribute__((ext_vector_type(8))) short short8;
typedef __attribute__((ext_vector_type(4))) float f32x4;

__device__ __forceinline__ unsigned short f2bf(float x) {
    union { float f; unsigned int u; } v; v.f = x;
    unsigned int r = v.u + 0x7fffu + ((v.u >> 16) & 1u);
    return (unsigned short)(r >> 16);
}
__device__ __forceinline__ float bf2f(unsigned short h) {
    union { unsigned int u; float f; } v; v.u = ((unsigned int)h) << 16;
    return v.f;
}

// async global->LDS 16B/lane; dst wave-uniform base (HW adds lane*16)
__device__ __forceinline__ void glds16(const void* g, void* l) {
    __builtin_amdgcn_global_load_lds(
        (const __attribute__((address_space(1))) void*)g,
        (__attribute__((address_space(3))) void*)l, 16, 0, 0);
}
#define MEMFENCE asm volatile("" ::: "memory")

// ---------------------------------------------------------------------------
// Workspace layouts identical to rounds 4-7:
//   blob0/blob1: [32 t][64 by][2 s][4 jf][4 kg][16 col][8 el] bf16 frag-ordered
//   bcJ: [4096] f32 J-interleaved fused biases
//   hTa/hTb: [32 t][4 bx][2 s][8 mf][4 kg][16 row][8 el] bf16 hi/lo
// ---------------------------------------------------------------------------

__global__ void prep_w(const float* __restrict__ wih,
                       const float* __restrict__ whh,
                       unsigned short* __restrict__ blob0,
                       unsigned short* __restrict__ blob1)
{
    const unsigned int f = blockIdx.x * 256 + threadIdx.x;  // 0..2^22-1
    const int el = f & 7;
    const int col = (f >> 3) & 15;
    const int kg = (f >> 7) & 3;
    const int jf = (f >> 9) & 3;
    const int by = (f >> 11) & 63;
    const int t  = (f >> 17) & 31;
    const int b  = blockIdx.y;      // blob select

    const int J = by * 64 + jf * 16 + col;
    const int g = J & 3;
    const long j = J >> 2;
    const long k = t * 32 + kg * 8 + el;

    float v = 0.f;
    if (b == 1) {
        if (g == 0)      v = wih[j*1024 + k]           + whh[j*1024 + k];
        else if (g == 1) v = wih[(1024+j)*1024 + k]    + whh[(1024+j)*1024 + k];
        else if (g == 2) v = wih[(2048+j)*1024 + k];
        else             v = whh[(2048+j)*1024 + k];
    } else {
        if (g == 0)      v = whh[j*1024 + k];
        else if (g == 1) v = whh[(1024+j)*1024 + k];
        else if (g == 2) v = 0.f;
        else             v = whh[(2048+j)*1024 + k];
    }
    const unsigned short hi = f2bf(v);
    const unsigned short lo = f2bf(v - bf2f(hi));

    unsigned short* blob = (b == 0) ? blob0 : blob1;
    const long base = ((long)(t*64 + by)*2) * 2048 + jf*512 + kg*128 + col*8 + el;
    blob[base]        = hi;
    blob[base + 2048] = lo;
}

__global__ void prep_bcJ(const float* __restrict__ bih,
                         const float* __restrict__ bhh,
                         float* __restrict__ bcJ)
{
    const int J = blockIdx.x * 256 + threadIdx.x;   // 0..4095
    const int g = J & 3;
    const int j = J >> 2;
    float v;
    if (g == 0)      v = bih[j]        + bhh[j];
    else if (g == 1) v = bih[1024 + j] + bhh[1024 + j];
    else if (g == 2) v = bih[2048 + j];
    else             v = bhh[2048 + j];
    bcJ[J] = v;
}

// c [512][1024] fp32 -> hT fragment layout (hi/lo bf16)
__global__ void prep_h0(const float* __restrict__ c,
                        unsigned short* __restrict__ hT)
{
    const int f = blockIdx.x * 256 + threadIdx.x;   // 0..65535
    const int ko = f & 127;
    const int m  = f >> 7;
    const long k0 = (long)ko * 8;
    const int t  = ko >> 2;
    const int kg = ko & 3;
    const int bx = m >> 7;
    const int mf = (m >> 4) & 7;
    const int row = m & 15;

    unsigned short hi[8], lo[8];
    #pragma unroll
    for (int e = 0; e < 8; ++e) {
        const float v = c[(long)m*1024 + k0 + e];
        hi[e] = f2bf(v);
        lo[e] = f2bf(v - bf2f(hi[e]));
    }
    const long base = ((long)(t*4 + bx)*2) * 4096 + mf*512 + kg*128 + row*8;
    #pragma unroll
    for (int e = 0; e < 8; ++e) { hT[base + e] = hi[e]; hT[base + 4096 + e] = lo[e]; }
}

// ---------------------------------------------------------------------------
// Fused GRU step, split-K 8-wave version.
// Grid 256 (1/CU), 512 threads (8 waves = 2/SIMD). Block tile 128m x 64J.
// Wave w: group gk=w>>2 handles K-half [gk*512, gk*512+512); wq=w&3 handles
// m rows [wq*32, wq*32+32). Per group: 16 K-chunks, 4 rotating LDS W bufs,
// 3-deep counted-vmcnt pipeline (6 vmem ops per wave per chunk).
// MFMA issued product-major: 8 independent acc chains per wave.
// Epilogue: both groups dump partial acc to LDS, 8 waves sum + gate math.
// ---------------------------------------------------------------------------
__global__ __launch_bounds__(512) void gru_step(
    const unsigned short* __restrict__ wblob,
    const unsigned short* __restrict__ hTr,
    unsigned short* __restrict__ hTw,
    const float* __restrict__ hprev, long hstride,
    const float* __restrict__ bcJ,
    float* __restrict__ outk)
{
    __shared__ __attribute__((aligned(16))) char smem[65536]; // 2 grp x 4 bufs x 8KB; epi D reuse

    const int tid  = threadIdx.x;
    const int lane = tid & 63;
    const int wv   = tid >> 6;        // 0..7
    const int gk   = wv >> 2;         // K-half group
    const int wq   = wv & 3;          // m-quarter

    const int id   = blockIdx.x;
    const int xcd  = id & 7;
    const int slot = id >> 3;
    const int by   = xcd * 8 + (slot & 7);   // 0..63  (J tile)
    const int bx   = slot >> 3;              // 0..3   (m tile)
    const long m0  = (long)bx * 128;

    const char* hbase = (const char*)hTr + (long)bx * 16384;   // + t*65536
    const char* wsrc  = (const char*)wblob + (long)by * 8192;  // + t*524288

    const int clo = lane & 15;
    const int chi = lane >> 4;

    // bias folded into group 0's accumulator init only
    f32x4 acc[2][4];
    #pragma unroll
    for (int jf = 0; jf < 4; ++jf) {
        const float b = (gk == 0) ? bcJ[by * 64 + jf * 16 + clo] : 0.f;
        acc[0][jf] = (f32x4){b, b, b, b};
        acc[1][jf] = (f32x4){b, b, b, b};
    }

    short8 A[4][4];   // [set = tt&3][h0, h1, l0, l1]
    char* gbuf = smem + gk * 32768;

    // issue group-local chunk tt: 4 A-loads (VGPR) then 2 W glds16 (LDS)
    auto issueG = [&](int tt) {
        if (tt < 16) {
            const long tg = (long)(gk * 16 + tt);
            const char* hs = hbase + tg * 65536;
            A[tt & 3][0] = *(const short8*)(hs + (2*wq + 0) * 1024 + lane * 16);
            A[tt & 3][1] = *(const short8*)(hs + (2*wq + 1) * 1024 + lane * 16);
            A[tt & 3][2] = *(const short8*)(hs + (8 + 2*wq + 0) * 1024 + lane * 16);
            A[tt & 3][3] = *(const short8*)(hs + (8 + 2*wq + 1) * 1024 + lane * 16);
            MEMFENCE;
            const char* ws = wsrc + tg * 524288;
            char* base = gbuf + (tt & 3) * 8192;
            glds16(ws + (0*4 + wq) * 1024 + lane * 16, base + (0*4 + wq) * 1024);
            glds16(ws + (4   + wq) * 1024 + lane * 16, base + (4   + wq) * 1024);
            MEMFENCE;
        }
    };

    // ---- prologue: fill 3 groups ----
    issueG(0);
    issueG(1);
    issueG(2);

    // ---- fully unrolled main loop (16 chunk-iterations) ----
    #pragma unroll
    for (int tt = 0; tt < 16; ++tt) {
        if (tt <= 13)      asm volatile("s_waitcnt vmcnt(12)" ::: "memory");
        else if (tt == 14) asm volatile("s_waitcnt vmcnt(6)"  ::: "memory");
        else               asm volatile("s_waitcnt vmcnt(0)"  ::: "memory");
        __builtin_amdgcn_s_barrier();

        issueG(tt + 3);    // overwrites buf[(tt-1)&3] — safe post-barrier

        const char* wb = gbuf + (tt & 3) * 8192;
        short8 bh[4], bl[4];
        #pragma unroll
        for (int jf = 0; jf < 4; ++jf) {
            bh[jf] = *(const short8*)(wb + jf * 1024 + lane * 16);
            bl[jf] = *(const short8*)(wb + 4096 + jf * 1024 + lane * 16);
        }
        // product-major: 8 independent chains per product step
        #pragma unroll
        for (int jf = 0; jf < 4; ++jf) {
            acc[0][jf] = __builtin_amdgcn_mfma_f32_16x16x32_bf16(A[tt&3][0], bh[jf], acc[0][jf], 0, 0, 0);
            acc[1][jf] = __builtin_amdgcn_mfma_f32_16x16x32_bf16(A[tt&3][1], bh[jf], acc[1][jf], 0, 0, 0);
        }
        #pragma unroll
        for (int jf = 0; jf < 4; ++jf) {
            acc[0][jf] = __builtin_amdgcn_mfma_f32_16x16x32_bf16(A[tt&3][2], bh[jf], acc[0][jf], 0, 0, 0);
            acc[1][jf] = __builtin_amdgcn_mfma_f32_16x16x32_bf16(A[tt&3][3], bh[jf], acc[1][jf], 0, 0, 0);
        }
        #pragma unroll
        for (int jf = 0; jf < 4; ++jf) {
            acc[0][jf] = __builtin_amdgcn_mfma_f32_16x16x32_bf16(A[tt&3][0], bl[jf], acc[0][jf], 0, 0, 0);
            acc[1][jf] = __builtin_amdgcn_mfma_f32_16x16x32_bf16(A[tt&3][1], bl[jf], acc[1][jf], 0, 0, 0);
        }
    }

    __syncthreads();   // all LDS buf reads done; smem becomes epilogue scratch

    // ---- epilogue: cross-group reduce + gate math, all 8 waves ----
    float* D = (float*)smem;               // [8 region][1024 f32] = 32 KB
    const int dreg = gk * 4 + wq;

    #pragma unroll
    for (int mf = 0; mf < 2; ++mf) {
        #pragma unroll
        for (int jf = 0; jf < 4; ++jf)
            #pragma unroll
            for (int r = 0; r < 4; ++r)
                D[dreg*1024 + (chi*4 + r)*64 + jf*16 + clo] = acc[mf][jf][r];
        __syncthreads();

        #pragma unroll
        for (int p = 0; p < 2; ++p) {
            const int it  = tid + p * 512;   // 0..1023
            const int row = it >> 4;         // 0..63
            const int jj  = it & 15;
            const int wqr = row >> 4;
            const int r16 = row & 15;
            const float4 g0 = *(const float4*)&D[wqr*1024 + r16*64 + jj*4];
            const float4 g1 = *(const float4*)&D[4096 + wqr*1024 + r16*64 + jj*4];
            const long m = m0 + wqr*32 + mf*16 + r16;
            const long j = (long)by * 16 + jj;

            const float hp = hprev[m * hstride + j];
            const float rr = 1.f / (1.f + expf(-(g0.x + g1.x)));
            const float zz = 1.f / (1.f + expf(-(g0.y + g1.y)));
            const float nn = tanhf(fmaf(rr, g0.w + g1.w, g0.z + g1.z));
            const float o  = nn + zz * (hp - nn);

            outk[m * KH + j] = o;

            const unsigned short hi = f2bf(o);
            const unsigned short lo = f2bf(o - bf2f(hi));
            const int mfh = wqr * 2 + mf;
            const int t2  = by >> 1;
            const int kg2 = (int)((j & 31) >> 3);
            const long hb = ((long)(t2*4 + bx)*2) * 4096
                          + mfh * 512 + kg2 * 128 + r16 * 8 + (jj & 7);
            hTw[hb]        = hi;
            hTw[hb + 4096] = lo;
        }
        __syncthreads();
    }
}

// ---------------------------------------------------------------------------
extern "C" void kernel_launch(void* const* d_in, const int* in_sizes, int n_in,
                              void* d_out, int out_size, void* d_ws, size_t ws_size,
                              hipStream_t stream)
{
    const float* c   = (const float*)d_in[0];
    // d_in[1] = K (fixed 96)
    const float* wih = (const float*)d_in[2];
    const float* whh = (const float*)d_in[3];
    const float* bih = (const float*)d_in[4];
    const float* bhh = (const float*)d_in[5];
    float* out = (float*)d_out;

    unsigned short* blob0 = (unsigned short*)d_ws;            // 8.39M ushort
    unsigned short* blob1 = blob0 + 8388608L;
    float*          bcJ   = (float*)(blob1 + 8388608L);       // 4096 f32
    unsigned short* hTa   = (unsigned short*)(bcJ + 4096);    // 1M ushort
    unsigned short* hTb   = hTa + 1048576L;

    prep_w  <<<dim3(16384, 2), 256, 0, stream>>>(wih, whh, blob0, blob1);
    prep_bcJ<<<dim3(16),       256, 0, stream>>>(bih, bhh, bcJ);
    prep_h0 <<<dim3(256),      256, 0, stream>>>(c, hTa);

    for (int k = 0; k < KSTEPS; ++k) {
        const unsigned short* wb  = (k == 0) ? blob0 : blob1;
        const unsigned short* hTr = (k & 1) ? hTb : hTa;
        unsigned short*       hTw = (k & 1) ? hTa : hTb;
        const float* hprev = (k == 0) ? c : (out + (long)(k - 1) * H);
        const long hstride = (k == 0) ? (long)H : KH;
        gru_step<<<dim3(256), 512, 0, stream>>>(wb, hTr, hTw, hprev, hstride,
                                                bcJ, out + (long)k * H);
    }
}